// Round 8
// baseline (170.017 us; speedup 1.0000x reference)
//
#include <hip/hip_runtime.h>

// CoordinateLoss: masked Kabsch (Horn quaternion) + Huber loss.
// B=256, S=16384, fp32 coords, int32 mask. 4 stream-ordered kernels.
//
// R6: no single-address global atomics (85us serialized tail). R5: power
// iteration on N/fro only (fp32 overflow otherwise). R7: AoS 12B/point loads
// at lane-stride-48B are transaction-split (2.7 TB/s ceiling) -> stage tiles
// through LDS: coalesced float4 global loads, per-point LDS reads at
// lane-stride-3-dwords (2 lanes/bank = free).

#define NB 256       // batches
#define NS 16384     // points per batch
#define TPB 256      // threads per block
#define TILE 2048    // points per block
#define HALF 1024    // points per LDS stage
#define PB (NS / TILE)       // 8 blocks per batch
#define NBLK (NB * PB)       // 2048 streaming blocks

__device__ __forceinline__ float wave_sum(float v) {
#pragma unroll
    for (int o = 32; o > 0; o >>= 1) v += __shfl_xor(v, o, 64);
    return v;
}

__device__ __forceinline__ float huber(float d) {
    float a = fabsf(d);
    return a < 1.f ? 0.5f * d * d : a - 0.5f;
}

// ---- kernel 1: partial sums of (cnt, Sp[3], St[3], Spt[9]) per block ----
__global__ __launch_bounds__(TPB, 4) void reduce_kernel(
    const float* __restrict__ pred, const float* __restrict__ tgt,
    const int* __restrict__ mask, float* __restrict__ part)
{
    const int b = blockIdx.y, j = blockIdx.x, t = threadIdx.x;
    const long pt0 = (long)b * NS + (long)j * TILE;
    const float4* pf4 = reinterpret_cast<const float4*>(pred + pt0 * 3);
    const float4* tf4 = reinterpret_cast<const float4*>(tgt + pt0 * 3);
    const int4*   mi4 = reinterpret_cast<const int4*>(mask + pt0);

    __shared__ float sP[HALF * 3];   // 12 KB raw AoS copy
    __shared__ float sT[HALF * 3];   // 12 KB
    __shared__ int   sM[HALF];       // 4 KB
    float4* sP4 = reinterpret_cast<float4*>(sP);
    float4* sT4 = reinterpret_cast<float4*>(sT);
    int4*   sM4 = reinterpret_cast<int4*>(sM);

    float acc[16];
#pragma unroll
    for (int i = 0; i < 16; ++i) acc[i] = 0.f;

    // half 0: coalesced global loads (lane-contiguous float4)
    float4 gp0 = pf4[t], gp1 = pf4[t + 256], gp2 = pf4[t + 512];
    float4 gt0 = tf4[t], gt1 = tf4[t + 256], gt2 = tf4[t + 512];
    int4   gm  = mi4[t];
    sP4[t] = gp0; sP4[t + 256] = gp1; sP4[t + 512] = gp2;
    sT4[t] = gt0; sT4[t + 256] = gt1; sT4[t + 512] = gt2;
    sM4[t] = gm;
    __syncthreads();

    // prefetch half 1 globals while half 0 is consumed from LDS
    float4 hp0 = pf4[768 + t], hp1 = pf4[1024 + t], hp2 = pf4[1280 + t];
    float4 ht0 = tf4[768 + t], ht1 = tf4[1024 + t], ht2 = tf4[1280 + t];
    int4   hm  = mi4[256 + t];

#pragma unroll
    for (int k = 0; k < 4; ++k) {      // points t, t+256, t+512, t+768
        const int p = t + (k << 8);
        const float mk = (float)sM[p];
        const float px = sP[3*p], py = sP[3*p+1], pz = sP[3*p+2];
        const float tx = sT[3*p], ty = sT[3*p+1], tz = sT[3*p+2];
        const float mp0 = mk * px, mp1 = mk * py, mp2 = mk * pz;
        acc[0] += mk;
        acc[1] += mp0;       acc[2] += mp1;       acc[3] += mp2;
        acc[4] += mk * tx;   acc[5] += mk * ty;   acc[6] += mk * tz;
        acc[7]  += mp0 * tx; acc[8]  += mp0 * ty; acc[9]  += mp0 * tz;
        acc[10] += mp1 * tx; acc[11] += mp1 * ty; acc[12] += mp1 * tz;
        acc[13] += mp2 * tx; acc[14] += mp2 * ty; acc[15] += mp2 * tz;
    }
    __syncthreads();

    // half 1
    sP4[t] = hp0; sP4[t + 256] = hp1; sP4[t + 512] = hp2;
    sT4[t] = ht0; sT4[t + 256] = ht1; sT4[t + 512] = ht2;
    sM4[t] = hm;
    __syncthreads();
#pragma unroll
    for (int k = 0; k < 4; ++k) {
        const int p = t + (k << 8);
        const float mk = (float)sM[p];
        const float px = sP[3*p], py = sP[3*p+1], pz = sP[3*p+2];
        const float tx = sT[3*p], ty = sT[3*p+1], tz = sT[3*p+2];
        const float mp0 = mk * px, mp1 = mk * py, mp2 = mk * pz;
        acc[0] += mk;
        acc[1] += mp0;       acc[2] += mp1;       acc[3] += mp2;
        acc[4] += mk * tx;   acc[5] += mk * ty;   acc[6] += mk * tz;
        acc[7]  += mp0 * tx; acc[8]  += mp0 * ty; acc[9]  += mp0 * tz;
        acc[10] += mp1 * tx; acc[11] += mp1 * ty; acc[12] += mp1 * tz;
        acc[13] += mp2 * tx; acc[14] += mp2 * ty; acc[15] += mp2 * tz;
    }

#pragma unroll
    for (int i = 0; i < 16; ++i) acc[i] = wave_sum(acc[i]);
    __shared__ float red[4][16];
    const int wave = t >> 6, lane = t & 63;
    if (lane == 0) {
#pragma unroll
        for (int i = 0; i < 16; ++i) red[wave][i] = acc[i];
    }
    __syncthreads();
    if (t < 16)
        part[((b * PB + j) << 4) + t] =
            red[0][t] + red[1][t] + red[2][t] + red[3][t];
}

// ---- kernel 2: per-batch Kabsch via Horn quaternion ----
__global__ __launch_bounds__(NB) void svd_kernel(
    const float* __restrict__ part, float* __restrict__ RT)
{
    const int b = threadIdx.x;
    const float4* p4 = reinterpret_cast<const float4*>(part);
    float a[16];
#pragma unroll
    for (int i = 0; i < 16; ++i) a[i] = 0.f;
#pragma unroll
    for (int k = 0; k < PB; ++k) {
        const int row = (b * PB + k) << 2;
        float4 v0 = p4[row], v1 = p4[row+1], v2 = p4[row+2], v3 = p4[row+3];
        a[0]+=v0.x;  a[1]+=v0.y;  a[2]+=v0.z;  a[3]+=v0.w;
        a[4]+=v1.x;  a[5]+=v1.y;  a[6]+=v1.z;  a[7]+=v1.w;
        a[8]+=v2.x;  a[9]+=v2.y;  a[10]+=v2.z; a[11]+=v2.w;
        a[12]+=v3.x; a[13]+=v3.y; a[14]+=v3.z; a[15]+=v3.w;
    }
    const float cnt = a[0];
    const float inv = 1.f / cnt;
    const float cpx=a[1]*inv, cpy=a[2]*inv, cpz=a[3]*inv;
    const float ctx=a[4]*inv, cty=a[5]*inv, ctz=a[6]*inv;
    const float Sxx = a[7]  - cnt*cpx*ctx;
    const float Sxy = a[8]  - cnt*cpx*cty;
    const float Sxz = a[9]  - cnt*cpx*ctz;
    const float Syx = a[10] - cnt*cpy*ctx;
    const float Syy = a[11] - cnt*cpy*cty;
    const float Syz = a[12] - cnt*cpy*ctz;
    const float Szx = a[13] - cnt*cpz*ctx;
    const float Szy = a[14] - cnt*cpz*cty;
    const float Szz = a[15] - cnt*cpz*ctz;
    float N00 =  Sxx + Syy + Szz;
    float N01 =  Syz - Szy;
    float N02 =  Szx - Sxz;
    float N03 =  Sxy - Syx;
    float N11 =  Sxx - Syy - Szz;
    float N12 =  Sxy + Syx;
    float N13 =  Szx + Sxz;
    float N22 = -Sxx + Syy - Szz;
    float N23 =  Syz + Szy;
    float N33 = -Sxx - Syy + Szz;
    const float fro = sqrtf(N00*N00 + N11*N11 + N22*N22 + N33*N33 +
                2.f*(N01*N01 + N02*N02 + N03*N03 + N12*N12 + N13*N13 + N23*N23));
    // Scale: spectral radius of (N/fro + I) <= 2; 8 unnormalized iters grow
    // ||q|| <= 2^8, ||q||^2 <= 65536 -- no fp32 overflow (R5 fix).
    const float isc = 1.f / (fro + 1e-30f);
    N00*=isc; N01*=isc; N02*=isc; N03*=isc; N11*=isc;
    N12*=isc; N13*=isc; N22*=isc; N23*=isc; N33*=isc;

    float qw = 1.f, qx = 0.1f, qy = 0.2f, qz = 0.3f;
    for (int it = 0; it < 160; ++it) {
        float nw = N00*qw + N01*qx + N02*qy + N03*qz + qw;
        float nx = N01*qw + N11*qx + N12*qy + N13*qz + qx;
        float ny = N02*qw + N12*qx + N22*qy + N23*qz + qy;
        float nz = N03*qw + N13*qx + N23*qy + N33*qz + qz;
        if ((it & 7) == 7) {
            const float r = rsqrtf(nw*nw + nx*nx + ny*ny + nz*nz);
            nw *= r; nx *= r; ny *= r; nz *= r;
        }
        qw = nw; qx = nx; qy = ny; qz = nz;
    }
    const float r = rsqrtf(qw*qw + qx*qx + qy*qy + qz*qz);
    qw *= r; qx *= r; qy *= r; qz *= r;
    const float R00 = 1.f - 2.f*(qy*qy + qz*qz);
    const float R01 = 2.f*(qx*qy - qw*qz);
    const float R02 = 2.f*(qx*qz + qw*qy);
    const float R10 = 2.f*(qx*qy + qw*qz);
    const float R11 = 1.f - 2.f*(qx*qx + qz*qz);
    const float R12 = 2.f*(qy*qz - qw*qx);
    const float R20 = 2.f*(qx*qz - qw*qy);
    const float R21 = 2.f*(qy*qz + qw*qx);
    const float R22 = 1.f - 2.f*(qx*qx + qy*qy);
    float* o = RT + b * 16;
    o[0]=R00; o[1]=R01; o[2]=R02; o[3]=R10; o[4]=R11; o[5]=R12;
    o[6]=R20; o[7]=R21; o[8]=R22;
    o[9]  = ctx - (R00*cpx + R01*cpy + R02*cpz);
    o[10] = cty - (R10*cpx + R11*cpy + R12*cpz);
    o[11] = ctz - (R20*cpx + R21*cpy + R22*cpz);
    o[12] = cnt;
}

// ---- kernel 3: masked Huber of (R p + t - target), per-block partials ----
__global__ __launch_bounds__(TPB, 4) void loss_kernel(
    const float* __restrict__ pred, const float* __restrict__ tgt,
    const int* __restrict__ mask, const float* __restrict__ RT,
    float* __restrict__ lpart)
{
    const int b = blockIdx.y, j = blockIdx.x, t = threadIdx.x;
    const long pt0 = (long)b * NS + (long)j * TILE;
    const float4* pf4 = reinterpret_cast<const float4*>(pred + pt0 * 3);
    const float4* tf4 = reinterpret_cast<const float4*>(tgt + pt0 * 3);
    const int4*   mi4 = reinterpret_cast<const int4*>(mask + pt0);

    __shared__ float sP[HALF * 3];
    __shared__ float sT[HALF * 3];
    __shared__ int   sM[HALF];
    __shared__ float C[12];
    float4* sP4 = reinterpret_cast<float4*>(sP);
    float4* sT4 = reinterpret_cast<float4*>(sT);
    int4*   sM4 = reinterpret_cast<int4*>(sM);

    if (t < 12) C[t] = RT[b * 16 + t];

    float ls = 0.f;
    float4 gp0 = pf4[t], gp1 = pf4[t + 256], gp2 = pf4[t + 512];
    float4 gt0 = tf4[t], gt1 = tf4[t + 256], gt2 = tf4[t + 512];
    int4   gm  = mi4[t];
    sP4[t] = gp0; sP4[t + 256] = gp1; sP4[t + 512] = gp2;
    sT4[t] = gt0; sT4[t + 256] = gt1; sT4[t + 512] = gt2;
    sM4[t] = gm;
    __syncthreads();

    float4 hp0 = pf4[768 + t], hp1 = pf4[1024 + t], hp2 = pf4[1280 + t];
    float4 ht0 = tf4[768 + t], ht1 = tf4[1024 + t], ht2 = tf4[1280 + t];
    int4   hm  = mi4[256 + t];

#pragma unroll
    for (int k = 0; k < 4; ++k) {
        const int p = t + (k << 8);
        const float mk = (float)sM[p];
        const float px = sP[3*p], py = sP[3*p+1], pz = sP[3*p+2];
        const float tx = sT[3*p], ty = sT[3*p+1], tz = sT[3*p+2];
        const float ax = C[0]*px + C[1]*py + C[2]*pz + C[9];
        const float ay = C[3]*px + C[4]*py + C[5]*pz + C[10];
        const float az = C[6]*px + C[7]*py + C[8]*pz + C[11];
        ls += mk * (huber(ax - tx) + huber(ay - ty) + huber(az - tz));
    }
    __syncthreads();

    sP4[t] = hp0; sP4[t + 256] = hp1; sP4[t + 512] = hp2;
    sT4[t] = ht0; sT4[t + 256] = ht1; sT4[t + 512] = ht2;
    sM4[t] = hm;
    __syncthreads();
#pragma unroll
    for (int k = 0; k < 4; ++k) {
        const int p = t + (k << 8);
        const float mk = (float)sM[p];
        const float px = sP[3*p], py = sP[3*p+1], pz = sP[3*p+2];
        const float tx = sT[3*p], ty = sT[3*p+1], tz = sT[3*p+2];
        const float ax = C[0]*px + C[1]*py + C[2]*pz + C[9];
        const float ay = C[3]*px + C[4]*py + C[5]*pz + C[10];
        const float az = C[6]*px + C[7]*py + C[8]*pz + C[11];
        ls += mk * (huber(ax - tx) + huber(ay - ty) + huber(az - tz));
    }

    ls = wave_sum(ls);
    __shared__ float red[4];
    const int wave = t >> 6, lane = t & 63;
    if (lane == 0) red[wave] = ls;
    __syncthreads();
    if (t == 0) lpart[b * PB + j] = red[0] + red[1] + red[2] + red[3];
}

// ---- kernel 4: final scalar = sum(lpart) / sum(cnt) ----
__global__ __launch_bounds__(NB) void final_kernel(
    const float* __restrict__ lpart, const float* __restrict__ RT,
    float* __restrict__ out)
{
    const int tid = threadIdx.x;
    float ls = 0.f;
#pragma unroll
    for (int k = 0; k < PB; ++k) ls += lpart[tid + NB * k];
    float cs = RT[tid * 16 + 12];
    ls = wave_sum(ls);
    cs = wave_sum(cs);
    __shared__ float rl[4], rc[4];
    const int wave = tid >> 6, lane = tid & 63;
    if (lane == 0) { rl[wave] = ls; rc[wave] = cs; }
    __syncthreads();
    if (tid == 0)
        out[0] = (rl[0]+rl[1]+rl[2]+rl[3]) / (rc[0]+rc[1]+rc[2]+rc[3]);
}

extern "C" void kernel_launch(void* const* d_in, const int* in_sizes, int n_in,
                              void* d_out, int out_size, void* d_ws, size_t ws_size,
                              hipStream_t stream) {
    const float* pred = (const float*)d_in[0];
    const float* tgt  = (const float*)d_in[1];
    const int*   mask = (const int*)d_in[2];
    float* out = (float*)d_out;

    // ws layout (floats): part[2048][16] | RT[256][16] | lpart[2048]
    float* part  = (float*)d_ws;
    float* RT    = part + NBLK * 16;
    float* lpart = RT + NB * 16;

    dim3 grid(PB, NB);
    reduce_kernel<<<grid, TPB, 0, stream>>>(pred, tgt, mask, part);
    svd_kernel<<<1, NB, 0, stream>>>(part, RT);
    loss_kernel<<<grid, TPB, 0, stream>>>(pred, tgt, mask, RT, lpart);
    final_kernel<<<1, NB, 0, stream>>>(lpart, RT, out);
}

// Round 9
// 167.725 us; speedup vs baseline: 1.0137x; 1.0137x over previous
//
#include <hip/hip_runtime.h>

// CoordinateLoss: masked Kabsch (Horn quaternion) + Huber loss.
// B=256, S=16384, fp32 coords, int32 mask. 4 stream-ordered kernels.
//
// Journal: R6: no single-address global atomics (60us serialized tail).
// R5: power iteration on N/fro only (unscaled overflows fp32 at norm-every-8).
// R8: LDS-staged coalesced loads == AoS loads == 41us for first pass ->
// transaction pattern is NOT the limiter. R9 experiment: max block count
// (4096), single-burst 7 independent loads/thread, __launch_bounds__(256,8)
// -> discriminates occupancy/MLP-limited vs first-touch-after-restore wall.

#define NB 256       // batches
#define NS 16384     // points per batch
#define TPB 256      // threads per block
#define PPT 4        // points per thread
#define CHUNKS (NS / (TPB * PPT))   // 16 blocks per batch
#define NBLK (NB * CHUNKS)          // 4096 streaming blocks

__device__ __forceinline__ float wave_sum(float v) {
#pragma unroll
    for (int o = 32; o > 0; o >>= 1) v += __shfl_xor(v, o, 64);
    return v;
}

__device__ __forceinline__ float huber(float d) {
    float a = fabsf(d);
    return a < 1.f ? 0.5f * d * d : a - 0.5f;
}

// ---- kernel 1: partial sums of (cnt, Sp[3], St[3], Spt[9]) per block ----
__global__ __launch_bounds__(TPB, 8) void reduce_kernel(
    const float* __restrict__ pred, const float* __restrict__ tgt,
    const int* __restrict__ mask, float* __restrict__ part)
{
    const int b = blockIdx.y, j = blockIdx.x, tid = threadIdx.x;
    const long base = (long)b * NS + (long)(j * TPB + tid) * PPT;
    const float4* p4 = reinterpret_cast<const float4*>(pred + base * 3);
    const float4* t4 = reinterpret_cast<const float4*>(tgt + base * 3);
    // 7 independent loads, one burst (max MLP)
    const float4 pA = p4[0], pB = p4[1], pC = p4[2];
    const float4 tA = t4[0], tB = t4[1], tC = t4[2];
    const int4 m4 = *reinterpret_cast<const int4*>(mask + base);
    float P[4][3] = {{pA.x,pA.y,pA.z},{pA.w,pB.x,pB.y},{pB.z,pB.w,pC.x},{pC.y,pC.z,pC.w}};
    float T[4][3] = {{tA.x,tA.y,tA.z},{tA.w,tB.x,tB.y},{tB.z,tB.w,tC.x},{tC.y,tC.z,tC.w}};
    float m[4] = {(float)m4.x,(float)m4.y,(float)m4.z,(float)m4.w};

    float acc[16];
#pragma unroll
    for (int i = 0; i < 16; ++i) acc[i] = 0.f;
#pragma unroll
    for (int k = 0; k < PPT; ++k) {
        const float mk = m[k];
        const float mp0 = mk * P[k][0], mp1 = mk * P[k][1], mp2 = mk * P[k][2];
        acc[0] += mk;
        acc[1] += mp0;            acc[2] += mp1;            acc[3] += mp2;
        acc[4] += mk * T[k][0];   acc[5] += mk * T[k][1];   acc[6] += mk * T[k][2];
        acc[7]  += mp0 * T[k][0]; acc[8]  += mp0 * T[k][1]; acc[9]  += mp0 * T[k][2];
        acc[10] += mp1 * T[k][0]; acc[11] += mp1 * T[k][1]; acc[12] += mp1 * T[k][2];
        acc[13] += mp2 * T[k][0]; acc[14] += mp2 * T[k][1]; acc[15] += mp2 * T[k][2];
    }
#pragma unroll
    for (int i = 0; i < 16; ++i) acc[i] = wave_sum(acc[i]);

    __shared__ float red[4][16];
    const int wave = tid >> 6, lane = tid & 63;
    if (lane == 0) {
#pragma unroll
        for (int i = 0; i < 16; ++i) red[wave][i] = acc[i];
    }
    __syncthreads();
    if (tid < 16)
        part[((b * CHUNKS + j) << 4) + tid] =
            red[0][tid] + red[1][tid] + red[2][tid] + red[3][tid];
}

// ---- kernel 2: per-batch Kabsch via Horn quaternion ----
__global__ __launch_bounds__(NB) void svd_kernel(
    const float* __restrict__ part, float* __restrict__ RT)
{
    const int b = threadIdx.x;
    const float4* p4 = reinterpret_cast<const float4*>(part);
    float a[16];
#pragma unroll
    for (int i = 0; i < 16; ++i) a[i] = 0.f;
#pragma unroll
    for (int k = 0; k < CHUNKS; ++k) {
        const int row = (b * CHUNKS + k) << 2;   // float4 units
        float4 v0 = p4[row], v1 = p4[row+1], v2 = p4[row+2], v3 = p4[row+3];
        a[0]+=v0.x;  a[1]+=v0.y;  a[2]+=v0.z;  a[3]+=v0.w;
        a[4]+=v1.x;  a[5]+=v1.y;  a[6]+=v1.z;  a[7]+=v1.w;
        a[8]+=v2.x;  a[9]+=v2.y;  a[10]+=v2.z; a[11]+=v2.w;
        a[12]+=v3.x; a[13]+=v3.y; a[14]+=v3.z; a[15]+=v3.w;
    }
    const float cnt = a[0];
    const float inv = 1.f / cnt;
    const float cpx=a[1]*inv, cpy=a[2]*inv, cpz=a[3]*inv;
    const float ctx=a[4]*inv, cty=a[5]*inv, ctz=a[6]*inv;
    const float Sxx = a[7]  - cnt*cpx*ctx;
    const float Sxy = a[8]  - cnt*cpx*cty;
    const float Sxz = a[9]  - cnt*cpx*ctz;
    const float Syx = a[10] - cnt*cpy*ctx;
    const float Syy = a[11] - cnt*cpy*cty;
    const float Syz = a[12] - cnt*cpy*ctz;
    const float Szx = a[13] - cnt*cpz*ctx;
    const float Szy = a[14] - cnt*cpz*cty;
    const float Szz = a[15] - cnt*cpz*ctz;
    // Horn's 4x4 N: max-eigvec quaternion == Kabsch R with det(+1) fix.
    float N00 =  Sxx + Syy + Szz;
    float N01 =  Syz - Szy;
    float N02 =  Szx - Sxz;
    float N03 =  Sxy - Syx;
    float N11 =  Sxx - Syy - Szz;
    float N12 =  Sxy + Syx;
    float N13 =  Szx + Sxz;
    float N22 = -Sxx + Syy - Szz;
    float N23 =  Syz + Szy;
    float N33 = -Sxx - Syy + Szz;
    const float fro = sqrtf(N00*N00 + N11*N11 + N22*N22 + N33*N33 +
                2.f*(N01*N01 + N02*N02 + N03*N03 + N12*N12 + N13*N13 + N23*N23));
    // Scale: spectral radius of (N/fro + I) <= 2; 8 unnormalized iters grow
    // ||q|| <= 2^8, ||q||^2 <= 65536 -- no fp32 overflow (R5 fix).
    const float isc = 1.f / (fro + 1e-30f);
    N00*=isc; N01*=isc; N02*=isc; N03*=isc; N11*=isc;
    N12*=isc; N13*=isc; N22*=isc; N23*=isc; N33*=isc;

    float qw = 1.f, qx = 0.1f, qy = 0.2f, qz = 0.3f;
    for (int it = 0; it < 96; ++it) {   // ratio <=~0.75/iter -> <1e-11 residual
        float nw = N00*qw + N01*qx + N02*qy + N03*qz + qw;
        float nx = N01*qw + N11*qx + N12*qy + N13*qz + qx;
        float ny = N02*qw + N12*qx + N22*qy + N23*qz + qy;
        float nz = N03*qw + N13*qx + N23*qy + N33*qz + qz;
        if ((it & 7) == 7) {
            const float r = rsqrtf(nw*nw + nx*nx + ny*ny + nz*nz);
            nw *= r; nx *= r; ny *= r; nz *= r;
        }
        qw = nw; qx = nx; qy = ny; qz = nz;
    }
    const float r = rsqrtf(qw*qw + qx*qx + qy*qy + qz*qz);
    qw *= r; qx *= r; qy *= r; qz *= r;
    const float R00 = 1.f - 2.f*(qy*qy + qz*qz);
    const float R01 = 2.f*(qx*qy - qw*qz);
    const float R02 = 2.f*(qx*qz + qw*qy);
    const float R10 = 2.f*(qx*qy + qw*qz);
    const float R11 = 1.f - 2.f*(qx*qx + qz*qz);
    const float R12 = 2.f*(qy*qz - qw*qx);
    const float R20 = 2.f*(qx*qz - qw*qy);
    const float R21 = 2.f*(qy*qz + qw*qx);
    const float R22 = 1.f - 2.f*(qx*qx + qy*qy);
    float* o = RT + b * 16;
    o[0]=R00; o[1]=R01; o[2]=R02; o[3]=R10; o[4]=R11; o[5]=R12;
    o[6]=R20; o[7]=R21; o[8]=R22;
    o[9]  = ctx - (R00*cpx + R01*cpy + R02*cpz);
    o[10] = cty - (R10*cpx + R11*cpy + R12*cpz);
    o[11] = ctz - (R20*cpx + R21*cpy + R22*cpz);
    o[12] = cnt;
}

// ---- kernel 3: masked Huber of (R p + t - target), per-block partials ----
__global__ __launch_bounds__(TPB, 8) void loss_kernel(
    const float* __restrict__ pred, const float* __restrict__ tgt,
    const int* __restrict__ mask, const float* __restrict__ RT,
    float* __restrict__ lpart)
{
    const int b = blockIdx.y, j = blockIdx.x, tid = threadIdx.x;
    __shared__ float C[12];
    if (tid < 12) C[tid] = RT[b * 16 + tid];
    __syncthreads();
    const long base = (long)b * NS + (long)(j * TPB + tid) * PPT;
    const float4* p4 = reinterpret_cast<const float4*>(pred + base * 3);
    const float4* t4 = reinterpret_cast<const float4*>(tgt + base * 3);
    const float4 pA = p4[0], pB = p4[1], pC = p4[2];
    const float4 tA = t4[0], tB = t4[1], tC = t4[2];
    const int4 m4 = *reinterpret_cast<const int4*>(mask + base);
    float P[4][3] = {{pA.x,pA.y,pA.z},{pA.w,pB.x,pB.y},{pB.z,pB.w,pC.x},{pC.y,pC.z,pC.w}};
    float T[4][3] = {{tA.x,tA.y,tA.z},{tA.w,tB.x,tB.y},{tB.z,tB.w,tC.x},{tC.y,tC.z,tC.w}};
    float m[4] = {(float)m4.x,(float)m4.y,(float)m4.z,(float)m4.w};

    float ls = 0.f;
#pragma unroll
    for (int k = 0; k < PPT; ++k) {
        const float ax = C[0]*P[k][0] + C[1]*P[k][1] + C[2]*P[k][2] + C[9];
        const float ay = C[3]*P[k][0] + C[4]*P[k][1] + C[5]*P[k][2] + C[10];
        const float az = C[6]*P[k][0] + C[7]*P[k][1] + C[8]*P[k][2] + C[11];
        ls += m[k] * (huber(ax - T[k][0]) + huber(ay - T[k][1]) + huber(az - T[k][2]));
    }
    ls = wave_sum(ls);
    __shared__ float red[4];
    const int wave = tid >> 6, lane = tid & 63;
    if (lane == 0) red[wave] = ls;
    __syncthreads();
    if (tid == 0) lpart[b * CHUNKS + j] = red[0] + red[1] + red[2] + red[3];
}

// ---- kernel 4: final scalar = sum(lpart) / sum(cnt) ----
__global__ __launch_bounds__(NB) void final_kernel(
    const float* __restrict__ lpart, const float* __restrict__ RT,
    float* __restrict__ out)
{
    const int tid = threadIdx.x;
    float ls = 0.f;
#pragma unroll
    for (int k = 0; k < CHUNKS; ++k) ls += lpart[tid + NB * k];
    float cs = RT[tid * 16 + 12];
    ls = wave_sum(ls);
    cs = wave_sum(cs);
    __shared__ float rl[4], rc[4];
    const int wave = tid >> 6, lane = tid & 63;
    if (lane == 0) { rl[wave] = ls; rc[wave] = cs; }
    __syncthreads();
    if (tid == 0)
        out[0] = (rl[0]+rl[1]+rl[2]+rl[3]) / (rc[0]+rc[1]+rc[2]+rc[3]);
}

extern "C" void kernel_launch(void* const* d_in, const int* in_sizes, int n_in,
                              void* d_out, int out_size, void* d_ws, size_t ws_size,
                              hipStream_t stream) {
    const float* pred = (const float*)d_in[0];
    const float* tgt  = (const float*)d_in[1];
    const int*   mask = (const int*)d_in[2];
    float* out = (float*)d_out;

    // ws layout (floats): part[4096][16] | RT[256][16] | lpart[4096]
    float* part  = (float*)d_ws;
    float* RT    = part + NBLK * 16;
    float* lpart = RT + NB * 16;

    dim3 grid(CHUNKS, NB);
    reduce_kernel<<<grid, TPB, 0, stream>>>(pred, tgt, mask, part);
    svd_kernel<<<1, NB, 0, stream>>>(part, RT);
    loss_kernel<<<grid, TPB, 0, stream>>>(pred, tgt, mask, RT, lpart);
    final_kernel<<<1, NB, 0, stream>>>(lpart, RT, out);
}